// Round 17
// baseline (19356.708 us; speedup 1.0000x reference)
//
#include <hip/hip_runtime.h>
#include <math.h>
#include <stdint.h>

#define NB 512
#define SL 128

// float offsets into g_ws
#define O_WHEF    0           // Wh_enc f32 [k/4][r=1024][4]  262144
#define O_WHDF    262144      // Wh_dec f32 [k/4][r][4]       262144
#define O_WRT     524288      // Wr f32 [k=256][col=512]      131072 (col<256: Wr_g else Wr_p)
#define O_WQGT    655360      // Wq_g^T f32 [k/4][j=256][4]   65536
#define O_WQPT    720896      //                              65536
#define O_ME64    786432      // f64 [e=4][r=1024]            8192 floats
#define O_MD64    794624      //                              8192
#define O_VE64    802816      // f64 [1024]                   2048
#define O_VD64    804864      //                              2048
#define O_X064    806912      //                              2048
#define O_HDH     808960      // enc-final h f64 [b][j]       262144
#define O_HDC     1071104     // enc-final c f64 [b][j]       262144
#define O_RG      1333248     // refg f32 [(b*128+s)][256]    16777216
#define O_RP      18110464    // refp                         16777216
#define O_HALL    34887680    // enc h f32 [(b*128+t)][256]   16777216
#define O_GUM     51664896    // gumbel f64 [t][b][s]         16777216 floats (8.4M doubles)
#define WS_FLOATS 68442112    // ~274 MB

__device__ __align__(16) float g_ws[WS_FLOATS];

__device__ __forceinline__ float sigf(float x) { return 1.0f / (1.0f + expf(-x)); }

// fast tanh via HW v_exp_f32; |err| ~1e-7 abs — used ONLY in attention u-loops (R11-proven)
__device__ __forceinline__ float tanh_fast(float x) {
    float e = __expf(2.0f * x);
    return 1.0f - 2.0f / (e + 1.0f);
}

__device__ __forceinline__ void tf2x32(uint32_t k0, uint32_t k1, uint32_t x0, uint32_t x1,
                                       uint32_t& o0, uint32_t& o1) {
    uint32_t ks2 = k0 ^ k1 ^ 0x1BD11BDAu;
    x0 += k0; x1 += k1;
#define RR(r) { x0 += x1; x1 = (x1 << r) | (x1 >> (32 - r)); x1 ^= x0; }
    RR(13) RR(15) RR(26) RR(6)   x0 += k1;  x1 += ks2 + 1u;
    RR(17) RR(29) RR(16) RR(24)  x0 += ks2; x1 += k0 + 2u;
    RR(13) RR(15) RR(26) RR(6)   x0 += k0;  x1 += k1 + 3u;
    RR(17) RR(29) RR(16) RR(24)  x0 += k1;  x1 += ks2 + 4u;
    RR(13) RR(15) RR(26) RR(6)   x0 += ks2; x1 += k0 + 5u;
#undef RR
    o0 = x0; o1 = x1;
}

// JAX partitionable-threefry: bits[n] = xor(threefry2x32(key,(0,n)))  [R3-verified exact]
__device__ __forceinline__ double gumbel_jax(uint32_t k0, uint32_t k1, uint32_t n) {
    uint32_t o0, o1; tf2x32(k0, k1, 0u, n, o0, o1);
    uint32_t bits = o0 ^ o1;
    float f = __uint_as_float((bits >> 9) | 0x3f800000u) - 1.0f;
    f = fmaxf(f, 1.17549435e-38f);
    return -log(-log((double)f));
}

// =============== pre-pack (identical to R16) ===============
__global__ void pre_k(const float* __restrict__ embed_W, const float* __restrict__ embed_b,
                      const float* __restrict__ Wi_enc, const float* __restrict__ Wh_enc,
                      const float* __restrict__ b_enc,
                      const float* __restrict__ Wi_dec, const float* __restrict__ Wh_dec,
                      const float* __restrict__ b_dec, const float* __restrict__ dec0,
                      const float* __restrict__ Wr_g, const float* __restrict__ Wr_p,
                      const float* __restrict__ Wq_g, const float* __restrict__ Wq_p) {
    float* ws = g_ws;
    double* ME = (double*)(ws + O_ME64);
    double* MD = (double*)(ws + O_MD64);
    double* VE = (double*)(ws + O_VE64);
    double* VD = (double*)(ws + O_VD64);
    double* X0 = (double*)(ws + O_X064);
    double* GUM = (double*)(ws + O_GUM);
    int i0 = blockIdx.x * blockDim.x + threadIdx.x;
    int np = gridDim.x * blockDim.x;
    for (int i = i0; i < 262144; i += np) {
        int k = i >> 10, r = i & 1023;
        int dst = ((k >> 2) << 12) + (r << 2) + (k & 3);
        ws[O_WHEF + dst] = Wh_enc[r * 256 + k];
        ws[O_WHDF + dst] = Wh_dec[r * 256 + k];
    }
    for (int i = i0; i < 131072; i += np) {
        int k = i >> 9, col = i & 511;
        ws[O_WRT + i] = (col < 256) ? Wr_g[col * 256 + k] : Wr_p[(col - 256) * 256 + k];
    }
    for (int i = i0; i < 65536; i += np) {
        int j = i & 255, k = i >> 8;
        int dst = ((k >> 2) << 10) + (j << 2) + (k & 3);
        ws[O_WQGT + dst] = Wq_g[j * 256 + k];
        ws[O_WQPT + dst] = Wq_p[j * 256 + k];
    }
    for (int i = i0; i < 4096; i += np) {
        int e = i >> 10, r = i & 1023;
        const float* we = embed_W + e * 256;
        const float* wa = Wi_enc + r * 256;
        const float* wb = Wi_dec + r * 256;
        double a = 0.0, b = 0.0;
        for (int E = 0; E < 256; ++E) { a += (double)we[E] * wa[E]; b += (double)we[E] * wb[E]; }
        ME[i] = a; MD[i] = b;
    }
    for (int r = i0; r < 1024; r += np) {
        const float* wa = Wi_enc + r * 256;
        const float* wb = Wi_dec + r * 256;
        double a = 0.0, b = 0.0, x = 0.0;
        for (int E = 0; E < 256; ++E) {
            a += (double)embed_b[E] * wa[E];
            b += (double)embed_b[E] * wb[E];
            x += (double)dec0[E] * wb[E];
        }
        VE[r] = a + (double)b_enc[r];
        VD[r] = b + (double)b_dec[r];
        X0[r] = x + (double)b_dec[r];
    }
    for (int i = i0; i < 8388608; i += np) {
        int t = i >> 16;
        uint32_t n = (uint32_t)(i & 65535);
        uint32_t kk0, kk1;
        tf2x32(0u, 1u, 0u, (uint32_t)t, kk0, kk1);
        GUM[i] = gumbel_jax(kk0, kk1, n);
    }
}

// =============== encoder (identical to R16) ===============
__global__ __launch_bounds__(1024) void enc_k(const float* __restrict__ problems) {
    float* ws = g_ws;
    const float4* Wh4 = (const float4*)(ws + O_WHEF);
    const double* ME = (const double*)(ws + O_ME64);
    const double* VE = (const double*)(ws + O_VE64);
    double* HDH = (double*)(ws + O_HDH);
    double* HDC = (double*)(ws + O_HDC);
    float* Hall = ws + O_HALL;

    const int bid = blockIdx.x, tid = threadIdx.x;
    const int b0 = bid << 1;
    __shared__ __align__(16) float hf[2][256];
    __shared__ double gbuf[2][4][256];
    const float4* hf40 = (const float4*)hf[0];
    const float4* hf41 = (const float4*)hf[1];

    if (tid < 512) hf[tid >> 8][tid & 255] = 0.f;
    double c = 0.0;
    __syncthreads();

    const int g = tid >> 8, j = tid & 255;
    const double vE = VE[tid];
    const double m0 = ME[tid], m1 = ME[1024 + tid], m2 = ME[2048 + tid], m3 = ME[3072 + tid];

    for (int t = 0; t < SL; ++t) {
        float4 p0 = *(const float4*)(problems + ((size_t)b0 * SL + t) * 4);
        float4 p1 = *(const float4*)(problems + ((size_t)(b0 + 1) * SL + t) * 4);
        double a0 = vE + (double)p0.x * m0 + (double)p0.y * m1 + (double)p0.z * m2 + (double)p0.w * m3;
        double a1 = vE + (double)p1.x * m0 + (double)p1.y * m1 + (double)p1.z * m2 + (double)p1.w * m3;
        if (t > 0) {
            float f0 = 0.f, f1 = 0.f;
#pragma unroll 4
            for (int k4 = 0; k4 < 64; ++k4) {
                float4 w = Wh4[(k4 << 10) + tid];
                float4 h0 = hf40[k4], h1 = hf41[k4];
                f0 = fmaf(h0.x, w.x, f0); f1 = fmaf(h1.x, w.x, f1);
                f0 = fmaf(h0.y, w.y, f0); f1 = fmaf(h1.y, w.y, f1);
                f0 = fmaf(h0.z, w.z, f0); f1 = fmaf(h1.z, w.z, f1);
                f0 = fmaf(h0.w, w.w, f0); f1 = fmaf(h1.w, w.w, f1);
            }
            a0 += (double)f0;
            a1 += (double)f1;
        }
        gbuf[0][g][j] = a0;
        gbuf[1][g][j] = a1;
        __syncthreads();
        if (tid < 512) {
            int bb = tid >> 8, jj = tid & 255;
            double g0 = gbuf[bb][0][jj], g1 = gbuf[bb][1][jj];
            double g2 = gbuf[bb][2][jj], g3 = gbuf[bb][3][jj];
            float ig = sigf((float)g0), fg = sigf((float)g1), gt = tanhf((float)g2), og = sigf((float)g3);
            c = (double)fg * c + (double)ig * (double)gt;
            double h = (double)og * (double)tanhf((float)c);
            hf[bb][jj] = (float)h;
            Hall[((size_t)(b0 + bb) * SL + t) * 256 + jj] = (float)h;
            if (t == SL - 1) {
                HDH[(size_t)(b0 + bb) * 256 + jj] = h;
                HDC[(size_t)(b0 + bb) * 256 + jj] = c;
            }
        }
        __syncthreads();
    }
}

// =============== refp GEMM (verbatim R8-proven) ===============
__global__ __launch_bounds__(256) void refp_gemm(const float* __restrict__ br_g,
                                                 const float* __restrict__ br_p) {
    float* ws = g_ws;
    const float* H = ws + O_HALL;
    const float* W = ws + O_WRT;
    const int bm = blockIdx.x, bn = blockIdx.y;
    const int tid = threadIdx.x;
    const int tr = tid >> 4, tc = tid & 15;
    __shared__ float As[32][65];
    __shared__ float Bs[32][65];
    float acc[4][4] = {};
    for (int kt = 0; kt < 8; ++kt) {
#pragma unroll
        for (int it = 0; it < 8; ++it) {
            int idx = it * 256 + tid;
            int m = idx >> 5, kk = idx & 31;
            As[kk][m] = H[(size_t)(bm * 64 + m) * 256 + kt * 32 + kk];
        }
#pragma unroll
        for (int it = 0; it < 8; ++it) {
            int idx = it * 256 + tid;
            int bk = idx >> 6, bc = idx & 63;
            Bs[bk][bc] = W[(size_t)(kt * 32 + bk) * 512 + bn * 64 + bc];
        }
        __syncthreads();
#pragma unroll
        for (int kk = 0; kk < 32; ++kk) {
            float a0 = As[kk][tr*4+0], a1 = As[kk][tr*4+1], a2 = As[kk][tr*4+2], a3 = As[kk][tr*4+3];
            float b0 = Bs[kk][tc*4+0], b1 = Bs[kk][tc*4+1], b2 = Bs[kk][tc*4+2], b3 = Bs[kk][tc*4+3];
            acc[0][0] = fmaf(a0,b0,acc[0][0]); acc[0][1] = fmaf(a0,b1,acc[0][1]);
            acc[0][2] = fmaf(a0,b2,acc[0][2]); acc[0][3] = fmaf(a0,b3,acc[0][3]);
            acc[1][0] = fmaf(a1,b0,acc[1][0]); acc[1][1] = fmaf(a1,b1,acc[1][1]);
            acc[1][2] = fmaf(a1,b2,acc[1][2]); acc[1][3] = fmaf(a1,b3,acc[1][3]);
            acc[2][0] = fmaf(a2,b0,acc[2][0]); acc[2][1] = fmaf(a2,b1,acc[2][1]);
            acc[2][2] = fmaf(a2,b2,acc[2][2]); acc[2][3] = fmaf(a2,b3,acc[2][3]);
            acc[3][0] = fmaf(a3,b0,acc[3][0]); acc[3][1] = fmaf(a3,b1,acc[3][1]);
            acc[3][2] = fmaf(a3,b2,acc[3][2]); acc[3][3] = fmaf(a3,b3,acc[3][3]);
        }
        __syncthreads();
    }
    const int colg = bn * 64 + tc * 4;
    float4 bias;
    float* outb;
    int colo;
    if (bn < 4) { bias = *(const float4*)(br_g + colg); outb = ws + O_RG; colo = colg; }
    else        { bias = *(const float4*)(br_p + colg - 256); outb = ws + O_RP; colo = colg - 256; }
#pragma unroll
    for (int i = 0; i < 4; ++i) {
        int row = bm * 64 + tr * 4 + i;
        float4 v = make_float4(acc[i][0] + bias.x, acc[i][1] + bias.y,
                               acc[i][2] + bias.z, acc[i][3] + bias.w);
        *(float4*)(outb + (size_t)row * 256 + colo) = v;
    }
}

// =============== decoder: wave-specialized producer(G)/consumer(A) pipeline ===============
// G-half (tid<512): streams gpre[r] = sum_k Wh[k][r]*h(t) for step t+1, chunked over slots.
// A-half (tid>=512): attention for step t (R9-proven 2-chunk splits) + jax-exact sampler.
__global__ __launch_bounds__(1024) void dec_k(const float* __restrict__ problems,
                                              const float* __restrict__ bq_g, const float* __restrict__ Vg,
                                              const float* __restrict__ bq_p, const float* __restrict__ Vp,
                                              float* __restrict__ out) {
    float* ws = g_ws;
    const float4* Wh4 = (const float4*)(ws + O_WHDF);
    const float4* WQG4 = (const float4*)(ws + O_WQGT);
    const float4* WQP4 = (const float4*)(ws + O_WQPT);
    const double* MD = (const double*)(ws + O_MD64);
    const double* VD = (const double*)(ws + O_VD64);
    const double* X0 = (const double*)(ws + O_X064);
    const double* HDH = (const double*)(ws + O_HDH);
    const double* HDC = (const double*)(ws + O_HDC);
    const double* GUM = (const double*)(ws + O_GUM);

    const int b = blockIdx.x, tid = threadIdx.x;
    __shared__ float refg_l[128][256];                 // 131072 B
    __shared__ __align__(16) float hf[256];            // 1024
    __shared__ float gpre[1024];                       // 4096
    __shared__ __align__(16) char scr[8192];           // gbuf(S0) ∪ pA/pQ/pP (slots)
    double (*gbuf)[256] = (double(*)[256])scr;         // 8192 B, S0 only
    float  (*pA)[256]   = (float(*)[256])scr;          // 2048 B
    float  (*pQ)[256]   = (float(*)[256])(scr + 2048); // 2048 B
    float  (*pP)[256]   = (float(*)[256])(scr + 4096); // 2048 B
    __shared__ float u_l[128];
    __shared__ float w_l[128];
    __shared__ unsigned char vis[128];
    __shared__ int lastA;
    const float4* hf4 = (const float4*)hf;

    // stage full refg into LDS (bit-identical data)
    {
        const float4* src = (const float4*)(ws + O_RG + (size_t)b * SL * 256);
        float4* dst = (float4*)&refg_l[0][0];
        for (int i = tid; i < 8192; i += 1024) dst[i] = src[i];
    }
    double c = 0.0;
    if (tid < 256) {
        hf[tid] = (float)HDH[(size_t)b * 256 + tid];
        c = HDC[(size_t)b * 256 + tid];
    }
    if (tid < 128) vis[tid] = 0;
    if (tid == 0) lastA = 0;
    __syncthreads();

    // pre-loop gpre for t=0: all 1024 threads, own row, k ascending (== R16 order)
    {
        float f0 = 0.f;
#pragma unroll 4
        for (int k4 = 0; k4 < 64; ++k4) {
            float4 w = Wh4[(k4 << 10) + tid];
            float4 h = hf4[k4];
            f0 = fmaf(h.x, w.x, f0);
            f0 = fmaf(h.y, w.y, f0);
            f0 = fmaf(h.z, w.z, f0);
            f0 = fmaf(h.w, w.w, f0);
        }
        gpre[tid] = f0;
    }
    __syncthreads();

    const bool isG = tid < 512;
    const int stid = tid & 511;
    const int kh = stid >> 8, jj = stid & 255;         // A-half: 2-chunk roles
    const int swave = stid >> 6, lane = tid & 63;
    const int d0 = lane, d1 = lane + 64, d2 = lane + 128, d3 = lane + 192;
    const int g = tid >> 8, j = tid & 255;             // S0 roles (all threads)
    const int r0 = stid, r1 = stid + 512;              // G-half rows
    const double vD = VD[tid], x0v = X0[tid];
    const double md0 = MD[tid], md1 = MD[1024 + tid], md2 = MD[2048 + tid], md3 = MD[3072 + tid];
    const float* refp = ws + O_RP + (size_t)b * SL * 256;
    const float* prb = problems + (size_t)b * SL * 4;

    // G-half slot chunk bounds over k4 = 0..63 (ascending -> bit-identical accumulation)
    const int CB[7] = {0, 11, 22, 33, 44, 54, 64};

#define G_CHUNK(ci)                                                        \
    if (isG) {                                                             \
        for (int k4 = CB[ci]; k4 < CB[ci + 1]; ++k4) {                     \
            float4 wA = Wh4[(k4 << 10) + r0];                              \
            float4 wB = Wh4[(k4 << 10) + r1];                              \
            float4 h = hf4[k4];                                            \
            fA = fmaf(h.x, wA.x, fA); fB = fmaf(h.x, wB.x, fB);            \
            fA = fmaf(h.y, wA.y, fA); fB = fmaf(h.y, wB.y, fB);            \
            fA = fmaf(h.z, wA.z, fA); fB = fmaf(h.z, wB.z, fB);            \
            fA = fmaf(h.w, wA.w, fA); fB = fmaf(h.w, wB.w, fB);            \
        }                                                                  \
    }

    for (int t = 0; t < SL; ++t) {
        // ---- S0: gate finalize (all 1024 threads, row = tid) ----
        double a0;
        if (t == 0) {
            a0 = x0v;
        } else {
            float4 p = *(const float4*)(prb + (lastA << 2));
            a0 = vD + (double)p.x * md0 + (double)p.y * md1 + (double)p.z * md2 + (double)p.w * md3;
        }
        a0 += (double)gpre[tid];
        gbuf[g][j] = a0;
        __syncthreads();                                   // B1
        if (tid < 256) {
            double g0 = gbuf[0][tid], g1 = gbuf[1][tid], g2 = gbuf[2][tid], g3 = gbuf[3][tid];
            float ig = sigf((float)g0), fg = sigf((float)g1), gt = tanhf((float)g2), og = sigf((float)g3);
            c = (double)fg * c + (double)ig * (double)gt;
            double h = (double)og * (double)tanhf((float)c);
            hf[tid] = (float)h;
        }
        __syncthreads();                                   // B2

        float fA = 0.f, fB = 0.f;                          // G accumulators (k ascending)

        // ---- S1: A: qp_g (2 k-halves, R9 split) | G: chunk 0 ----
        G_CHUNK(0)
        else {
            float qa = 0.f;
            const int kb4 = kh << 5;
#pragma unroll 4
            for (int kk4 = 0; kk4 < 32; ++kk4) {
                int k4 = kb4 + kk4;
                float4 wq = WQG4[(k4 << 8) + jj];
                float4 h = hf4[k4];
                qa = fmaf(h.x, wq.x, qa);
                qa = fmaf(h.y, wq.y, qa);
                qa = fmaf(h.z, wq.z, qa);
                qa = fmaf(h.w, wq.w, qa);
            }
            pA[kh][jj] = qa;
        }
        __syncthreads();                                   // B3

        // ---- S2: A: glimpse u (8 waves, stride 8) | G: chunk 1 ----
        G_CHUNK(1)
        else {
            const float q0 = pA[0][d0] + pA[1][d0] + bq_g[d0], v0 = Vg[d0];
            const float q1 = pA[0][d1] + pA[1][d1] + bq_g[d1], v1 = Vg[d1];
            const float q2 = pA[0][d2] + pA[1][d2] + bq_g[d2], v2 = Vg[d2];
            const float q3 = pA[0][d3] + pA[1][d3] + bq_g[d3], v3 = Vg[d3];
            for (int s = swave; s < SL; s += 8) {
                if (vis[s]) continue;
                const float* r = refg_l[s];
                float part = tanh_fast(q0 + r[d0]) * 10.f * v0;
                part = fmaf(tanh_fast(q1 + r[d1]) * 10.f, v1, part);
                part = fmaf(tanh_fast(q2 + r[d2]) * 10.f, v2, part);
                part = fmaf(tanh_fast(q3 + r[d3]) * 10.f, v3, part);
                for (int off = 32; off; off >>= 1) part += __shfl_xor(part, off, 64);
                if (lane == 0) u_l[s] = part;
            }
        }
        __syncthreads();                                   // B4

        // ---- S3: A: glimpse softmax (first A wave) | G: chunk 2 ----
        G_CHUNK(2)
        else if (swave == 0) {
            int s1 = lane, s2 = lane + 64;
            bool v1 = vis[s1], v2 = vis[s2];
            float m = fmaxf(v1 ? -1e30f : u_l[s1], v2 ? -1e30f : u_l[s2]);
            for (int off = 32; off; off >>= 1) m = fmaxf(m, __shfl_xor(m, off, 64));
            float e1 = v1 ? 0.f : expf(u_l[s1] - m);
            float e2 = v2 ? 0.f : expf(u_l[s2] - m);
            float den = e1 + e2;
            for (int off = 32; off; off >>= 1) den += __shfl_xor(den, off, 64);
            w_l[s1] = e1 / den;
            w_l[s2] = e2 / den;
        }
        __syncthreads();                                   // B5

        // ---- S4: A: q partials (2 s-halves of 64, R9 split) | G: chunk 3 ----
        G_CHUNK(3)
        else {
            const int s0q = kh << 6;
            float q = 0.f;
            for (int s = s0q; s < s0q + 64; ++s) {
                float w = w_l[s];
                if (w != 0.f) q = fmaf(w, refg_l[s][jj], q);
            }
            pQ[kh][jj] = q;
        }
        __syncthreads();                                   // B6

        // ---- S5: A: qp_p (2 k-halves, R9 split) | G: chunk 4 ----
        G_CHUNK(4)
        else {
            float qa = 0.f;
            const int kb4 = kh << 5;
            const float4* pQ0 = (const float4*)pQ[0];
            const float4* pQ1 = (const float4*)pQ[1];
#pragma unroll 4
            for (int kk4 = 0; kk4 < 32; ++kk4) {
                int k4 = kb4 + kk4;
                float4 wq = WQP4[(k4 << 8) + jj];
                float4 q0v = pQ0[k4], q1v = pQ1[k4];
                qa = fmaf(q0v.x + q1v.x, wq.x, qa);
                qa = fmaf(q0v.y + q1v.y, wq.y, qa);
                qa = fmaf(q0v.z + q1v.z, wq.z, qa);
                qa = fmaf(q0v.w + q1v.w, wq.w, qa);
            }
            pP[kh][jj] = qa;
        }
        __syncthreads();                                   // B7

        // ---- S6: A: pointer u (8 waves, refp global) | G: chunk 5 + store gpre ----
        G_CHUNK(5)
        else {
            const float q0 = pP[0][d0] + pP[1][d0] + bq_p[d0], v0 = Vp[d0];
            const float q1 = pP[0][d1] + pP[1][d1] + bq_p[d1], v1 = Vp[d1];
            const float q2 = pP[0][d2] + pP[1][d2] + bq_p[d2], v2 = Vp[d2];
            const float q3 = pP[0][d3] + pP[1][d3] + bq_p[d3], v3 = Vp[d3];
            for (int s = swave; s < SL; s += 8) {
                if (vis[s]) continue;
                const float* r = refp + (s << 8);
                float part = tanh_fast(q0 + r[d0]) * 10.f * v0;
                part = fmaf(tanh_fast(q1 + r[d1]) * 10.f, v1, part);
                part = fmaf(tanh_fast(q2 + r[d2]) * 10.f, v2, part);
                part = fmaf(tanh_fast(q3 + r[d3]) * 10.f, v3, part);
                for (int off = 32; off; off >>= 1) part += __shfl_xor(part, off, 64);
                if (lane == 0) u_l[s] = part;
            }
        }
        if (isG) { gpre[r0] = fA; gpre[r1] = fB; }
        __syncthreads();                                   // B8

        // ---- S7: A: sample (first A wave; jax-exact, GUM table) ----
        if (!isG && swave == 0) {
            int s1 = lane, s2 = lane + 64;
            bool v1 = vis[s1], v2 = vis[s2];
            float m = fmaxf(v1 ? -1e30f : u_l[s1], v2 ? -1e30f : u_l[s2]);
            for (int off = 32; off; off >>= 1) m = fmaxf(m, __shfl_xor(m, off, 64));
            float e1 = v1 ? 0.f : expf(u_l[s1] - m);
            float e2 = v2 ? 0.f : expf(u_l[s2] - m);
            float den = e1 + e2;
            for (int off = 32; off; off >>= 1) den += __shfl_xor(den, off, 64);
            const double* gt = GUM + ((size_t)t << 16) + (b << 7);
            double z1 = v1 ? -1.0e300 : (double)u_l[s1] + gt[s1];
            double z2 = v2 ? -1.0e300 : (double)u_l[s2] + gt[s2];
            double bz; int bi;
            if (z2 > z1) { bz = z2; bi = s2; } else { bz = z1; bi = s1; }
            for (int off = 32; off; off >>= 1) {
                double oz = __shfl_xor(bz, off, 64);
                int oi = __shfl_xor(bi, off, 64);
                if (oz > bz || (oz == bz && oi < bi)) { bz = oz; bi = oi; }
            }
            if (lane == 0) {
                float pr = expf(u_l[bi] - m) / den;
                out[t * NB + b] = pr;
                out[SL * NB + t * NB + b] = (float)bi;
                vis[bi] = 1;
                lastA = bi;
            }
        }
        __syncthreads();                                   // B9
    }
#undef G_CHUNK
}

extern "C" void kernel_launch(void* const* d_in, const int* in_sizes, int n_in,
                              void* d_out, int out_size, void* d_ws, size_t ws_size,
                              hipStream_t stream) {
    (void)d_ws; (void)ws_size; (void)n_in; (void)in_sizes; (void)out_size;
    const float* problems = (const float*)d_in[0];
    const float* embed_W  = (const float*)d_in[1];
    const float* embed_b  = (const float*)d_in[2];
    const float* Wi_enc   = (const float*)d_in[3];
    const float* Wh_enc   = (const float*)d_in[4];
    const float* b_enc    = (const float*)d_in[5];
    const float* Wi_dec   = (const float*)d_in[6];
    const float* Wh_dec   = (const float*)d_in[7];
    const float* b_dec    = (const float*)d_in[8];
    const float* dec0     = (const float*)d_in[9];
    const float* Wq_g     = (const float*)d_in[10];
    const float* bq_g     = (const float*)d_in[11];
    const float* Wr_g     = (const float*)d_in[12];
    const float* br_g     = (const float*)d_in[13];
    const float* V_g      = (const float*)d_in[14];
    const float* Wq_p     = (const float*)d_in[15];
    const float* bq_p     = (const float*)d_in[16];
    const float* Wr_p     = (const float*)d_in[17];
    const float* br_p     = (const float*)d_in[18];
    const float* V_p      = (const float*)d_in[19];
    float* outp = (float*)d_out;

    hipLaunchKernelGGL(pre_k, dim3(512), dim3(256), 0, stream,
                       embed_W, embed_b, Wi_enc, Wh_enc, b_enc,
                       Wi_dec, Wh_dec, b_dec, dec0, Wr_g, Wr_p, Wq_g, Wq_p);
    hipLaunchKernelGGL(enc_k, dim3(256), dim3(1024), 0, stream, problems);
    hipLaunchKernelGGL(refp_gemm, dim3(1024, 8), dim3(256), 0, stream, br_g, br_p);
    hipLaunchKernelGGL(dec_k, dim3(512), dim3(1024), 0, stream,
                       problems, bq_g, V_g, bq_p, V_p, outp);
}

// Round 18
// 8998.550 us; speedup vs baseline: 2.1511x; 2.1511x over previous
//
#include <hip/hip_runtime.h>
#include <math.h>
#include <stdint.h>

#define NB 512
#define SL 128

// float offsets into g_ws
#define O_WHEF    0           // Wh_enc f32 [k/4][r=1024][4]  262144
#define O_WHDF    262144      // Wh_dec f32 [k/4][r][4]       262144
#define O_WRT     524288      // Wr f32 [k=256][col=512]      131072 (col<256: Wr_g else Wr_p)
#define O_WQGT    655360      // Wq_g^T f32 [k/4][j=256][4]   65536
#define O_WQPT    720896      //                              65536
#define O_ME64    786432      // f64 [e=4][r=1024]            8192 floats
#define O_MD64    794624      //                              8192
#define O_VE64    802816      // f64 [1024]                   2048
#define O_VD64    804864      //                              2048
#define O_X064    806912      //                              2048
#define O_HDH     808960      // enc-final h f64 [b][j]       262144
#define O_HDC     1071104     // enc-final c f64 [b][j]       262144
#define O_RG      1333248     // refg f32 [(b*128+s)][256]    16777216
#define O_RP      18110464    // refp                         16777216
#define O_HALL    34887680    // enc h f32 [(b*128+t)][256]   16777216
#define O_GUM     51664896    // gumbel f64 [t][b][s]         16777216 floats (8.4M doubles)
#define WS_FLOATS 68442112    // ~274 MB

__device__ __align__(16) float g_ws[WS_FLOATS];

__device__ __forceinline__ float sigf(float x) { return 1.0f / (1.0f + expf(-x)); }

// fast tanh via HW v_exp_f32; |err| ~1e-7 abs — used ONLY in attention u-loops (R11-proven)
__device__ __forceinline__ float tanh_fast(float x) {
    float e = __expf(2.0f * x);
    return 1.0f - 2.0f / (e + 1.0f);
}

__device__ __forceinline__ void tf2x32(uint32_t k0, uint32_t k1, uint32_t x0, uint32_t x1,
                                       uint32_t& o0, uint32_t& o1) {
    uint32_t ks2 = k0 ^ k1 ^ 0x1BD11BDAu;
    x0 += k0; x1 += k1;
#define RR(r) { x0 += x1; x1 = (x1 << r) | (x1 >> (32 - r)); x1 ^= x0; }
    RR(13) RR(15) RR(26) RR(6)   x0 += k1;  x1 += ks2 + 1u;
    RR(17) RR(29) RR(16) RR(24)  x0 += ks2; x1 += k0 + 2u;
    RR(13) RR(15) RR(26) RR(6)   x0 += k0;  x1 += k1 + 3u;
    RR(17) RR(29) RR(16) RR(24)  x0 += k1;  x1 += ks2 + 4u;
    RR(13) RR(15) RR(26) RR(6)   x0 += ks2; x1 += k0 + 5u;
#undef RR
    o0 = x0; o1 = x1;
}

// JAX partitionable-threefry: bits[n] = xor(threefry2x32(key,(0,n)))  [R3-verified exact]
__device__ __forceinline__ double gumbel_jax(uint32_t k0, uint32_t k1, uint32_t n) {
    uint32_t o0, o1; tf2x32(k0, k1, 0u, n, o0, o1);
    uint32_t bits = o0 ^ o1;
    float f = __uint_as_float((bits >> 9) | 0x3f800000u) - 1.0f;
    f = fmaxf(f, 1.17549435e-38f);
    return -log(-log((double)f));
}

// =============== pre-pack (R14 + float4-group weight layouts) ===============
__global__ void pre_k(const float* __restrict__ embed_W, const float* __restrict__ embed_b,
                      const float* __restrict__ Wi_enc, const float* __restrict__ Wh_enc,
                      const float* __restrict__ b_enc,
                      const float* __restrict__ Wi_dec, const float* __restrict__ Wh_dec,
                      const float* __restrict__ b_dec, const float* __restrict__ dec0,
                      const float* __restrict__ Wr_g, const float* __restrict__ Wr_p,
                      const float* __restrict__ Wq_g, const float* __restrict__ Wq_p) {
    float* ws = g_ws;
    double* ME = (double*)(ws + O_ME64);
    double* MD = (double*)(ws + O_MD64);
    double* VE = (double*)(ws + O_VE64);
    double* VD = (double*)(ws + O_VD64);
    double* X0 = (double*)(ws + O_X064);
    double* GUM = (double*)(ws + O_GUM);
    int i0 = blockIdx.x * blockDim.x + threadIdx.x;
    int np = gridDim.x * blockDim.x;
    // Wh: [k/4][r][4]  (dst = (k>>2)*4096 + r*4 + (k&3))
    for (int i = i0; i < 262144; i += np) {
        int k = i >> 10, r = i & 1023;
        int dst = ((k >> 2) << 12) + (r << 2) + (k & 3);
        ws[O_WHEF + dst] = Wh_enc[r * 256 + k];
        ws[O_WHDF + dst] = Wh_dec[r * 256 + k];
    }
    for (int i = i0; i < 131072; i += np) {
        int k = i >> 9, col = i & 511;
        ws[O_WRT + i] = (col < 256) ? Wr_g[col * 256 + k] : Wr_p[(col - 256) * 256 + k];
    }
    // Wq^T: [k/4][j][4]  (dst = (k>>2)*1024 + j*4 + (k&3))
    for (int i = i0; i < 65536; i += np) {
        int j = i & 255, k = i >> 8;
        int dst = ((k >> 2) << 10) + (j << 2) + (k & 3);
        ws[O_WQGT + dst] = Wq_g[j * 256 + k];
        ws[O_WQPT + dst] = Wq_p[j * 256 + k];
    }
    for (int i = i0; i < 4096; i += np) {
        int e = i >> 10, r = i & 1023;
        const float* we = embed_W + e * 256;
        const float* wa = Wi_enc + r * 256;
        const float* wb = Wi_dec + r * 256;
        double a = 0.0, b = 0.0;
        for (int E = 0; E < 256; ++E) { a += (double)we[E] * wa[E]; b += (double)we[E] * wb[E]; }
        ME[i] = a; MD[i] = b;
    }
    for (int r = i0; r < 1024; r += np) {
        const float* wa = Wi_enc + r * 256;
        const float* wb = Wi_dec + r * 256;
        double a = 0.0, b = 0.0, x = 0.0;
        for (int E = 0; E < 256; ++E) {
            a += (double)embed_b[E] * wa[E];
            b += (double)embed_b[E] * wb[E];
            x += (double)dec0[E] * wb[E];
        }
        VE[r] = a + (double)b_enc[r];
        VD[r] = b + (double)b_dec[r];
        X0[r] = x + (double)b_dec[r];
    }
    for (int i = i0; i < 8388608; i += np) {
        int t = i >> 16;
        uint32_t n = (uint32_t)(i & 65535);
        uint32_t kk0, kk1;
        tf2x32(0u, 1u, 0u, (uint32_t)t, kk0, kk1);
        GUM[i] = gumbel_jax(kk0, kk1, n);
    }
}

// =============== encoder: gates only, float4 weight loads, grid 256 x 1024 ===============
__global__ __launch_bounds__(1024) void enc_k(const float* __restrict__ problems) {
    float* ws = g_ws;
    const float4* Wh4 = (const float4*)(ws + O_WHEF);
    const double* ME = (const double*)(ws + O_ME64);
    const double* VE = (const double*)(ws + O_VE64);
    double* HDH = (double*)(ws + O_HDH);
    double* HDC = (double*)(ws + O_HDC);
    float* Hall = ws + O_HALL;

    const int bid = blockIdx.x, tid = threadIdx.x;
    const int b0 = bid << 1;
    __shared__ __align__(16) float hf[2][256];
    __shared__ double gbuf[2][4][256];
    const float4* hf40 = (const float4*)hf[0];
    const float4* hf41 = (const float4*)hf[1];

    if (tid < 512) hf[tid >> 8][tid & 255] = 0.f;
    double c = 0.0;
    __syncthreads();

    const int g = tid >> 8, j = tid & 255;
    const double vE = VE[tid];
    const double m0 = ME[tid], m1 = ME[1024 + tid], m2 = ME[2048 + tid], m3 = ME[3072 + tid];

    for (int t = 0; t < SL; ++t) {
        float4 p0 = *(const float4*)(problems + ((size_t)b0 * SL + t) * 4);
        float4 p1 = *(const float4*)(problems + ((size_t)(b0 + 1) * SL + t) * 4);
        double a0 = vE + (double)p0.x * m0 + (double)p0.y * m1 + (double)p0.z * m2 + (double)p0.w * m3;
        double a1 = vE + (double)p1.x * m0 + (double)p1.y * m1 + (double)p1.z * m2 + (double)p1.w * m3;
        if (t > 0) {
            float f0 = 0.f, f1 = 0.f;
#pragma unroll 4
            for (int k4 = 0; k4 < 64; ++k4) {
                float4 w = Wh4[(k4 << 10) + tid];
                float4 h0 = hf40[k4], h1 = hf41[k4];
                f0 = fmaf(h0.x, w.x, f0); f1 = fmaf(h1.x, w.x, f1);
                f0 = fmaf(h0.y, w.y, f0); f1 = fmaf(h1.y, w.y, f1);
                f0 = fmaf(h0.z, w.z, f0); f1 = fmaf(h1.z, w.z, f1);
                f0 = fmaf(h0.w, w.w, f0); f1 = fmaf(h1.w, w.w, f1);
            }
            a0 += (double)f0;
            a1 += (double)f1;
        }
        gbuf[0][g][j] = a0;
        gbuf[1][g][j] = a1;
        __syncthreads();
        if (tid < 512) {
            int bb = tid >> 8, jj = tid & 255;
            double g0 = gbuf[bb][0][jj], g1 = gbuf[bb][1][jj];
            double g2 = gbuf[bb][2][jj], g3 = gbuf[bb][3][jj];
            float ig = sigf((float)g0), fg = sigf((float)g1), gt = tanhf((float)g2), og = sigf((float)g3);
            c = (double)fg * c + (double)ig * (double)gt;
            double h = (double)og * (double)tanhf((float)c);
            hf[bb][jj] = (float)h;
            Hall[((size_t)(b0 + bb) * SL + t) * 256 + jj] = (float)h;
            if (t == SL - 1) {
                HDH[(size_t)(b0 + bb) * 256 + jj] = h;
                HDC[(size_t)(b0 + bb) * 256 + jj] = c;
            }
        }
        __syncthreads();
    }
}

// =============== refp GEMM (verbatim R8-proven) ===============
__global__ __launch_bounds__(256) void refp_gemm(const float* __restrict__ br_g,
                                                 const float* __restrict__ br_p) {
    float* ws = g_ws;
    const float* H = ws + O_HALL;
    const float* W = ws + O_WRT;
    const int bm = blockIdx.x, bn = blockIdx.y;
    const int tid = threadIdx.x;
    const int tr = tid >> 4, tc = tid & 15;
    __shared__ float As[32][65];
    __shared__ float Bs[32][65];
    float acc[4][4] = {};
    for (int kt = 0; kt < 8; ++kt) {
#pragma unroll
        for (int it = 0; it < 8; ++it) {
            int idx = it * 256 + tid;
            int m = idx >> 5, kk = idx & 31;
            As[kk][m] = H[(size_t)(bm * 64 + m) * 256 + kt * 32 + kk];
        }
#pragma unroll
        for (int it = 0; it < 8; ++it) {
            int idx = it * 256 + tid;
            int bk = idx >> 6, bc = idx & 63;
            Bs[bk][bc] = W[(size_t)(kt * 32 + bk) * 512 + bn * 64 + bc];
        }
        __syncthreads();
#pragma unroll
        for (int kk = 0; kk < 32; ++kk) {
            float a0 = As[kk][tr*4+0], a1 = As[kk][tr*4+1], a2 = As[kk][tr*4+2], a3 = As[kk][tr*4+3];
            float b0 = Bs[kk][tc*4+0], b1 = Bs[kk][tc*4+1], b2 = Bs[kk][tc*4+2], b3 = Bs[kk][tc*4+3];
            acc[0][0] = fmaf(a0,b0,acc[0][0]); acc[0][1] = fmaf(a0,b1,acc[0][1]);
            acc[0][2] = fmaf(a0,b2,acc[0][2]); acc[0][3] = fmaf(a0,b3,acc[0][3]);
            acc[1][0] = fmaf(a1,b0,acc[1][0]); acc[1][1] = fmaf(a1,b1,acc[1][1]);
            acc[1][2] = fmaf(a1,b2,acc[1][2]); acc[1][3] = fmaf(a1,b3,acc[1][3]);
            acc[2][0] = fmaf(a2,b0,acc[2][0]); acc[2][1] = fmaf(a2,b1,acc[2][1]);
            acc[2][2] = fmaf(a2,b2,acc[2][2]); acc[2][3] = fmaf(a2,b3,acc[2][3]);
            acc[3][0] = fmaf(a3,b0,acc[3][0]); acc[3][1] = fmaf(a3,b1,acc[3][1]);
            acc[3][2] = fmaf(a3,b2,acc[3][2]); acc[3][3] = fmaf(a3,b3,acc[3][3]);
        }
        __syncthreads();
    }
    const int colg = bn * 64 + tc * 4;
    float4 bias;
    float* outb;
    int colo;
    if (bn < 4) { bias = *(const float4*)(br_g + colg); outb = ws + O_RG; colo = colg; }
    else        { bias = *(const float4*)(br_p + colg - 256); outb = ws + O_RP; colo = colg - 256; }
#pragma unroll
    for (int i = 0; i < 4; ++i) {
        int row = bm * 64 + tr * 4 + i;
        float4 v = make_float4(acc[i][0] + bias.x, acc[i][1] + bias.y,
                               acc[i][2] + bias.z, acc[i][3] + bias.w);
        *(float4*)(outb + (size_t)row * 256 + colo) = v;
    }
}

// =============== decoder: R14 structure, float4 weight loads ===============
__global__ __launch_bounds__(1024) void dec_k(const float* __restrict__ problems,
                                              const float* __restrict__ bq_g, const float* __restrict__ Vg,
                                              const float* __restrict__ bq_p, const float* __restrict__ Vp,
                                              float* __restrict__ out) {
    float* ws = g_ws;
    const float4* Wh4 = (const float4*)(ws + O_WHDF);
    const float4* WQG4 = (const float4*)(ws + O_WQGT);
    const float4* WQP4 = (const float4*)(ws + O_WQPT);
    const double* MD = (const double*)(ws + O_MD64);
    const double* VD = (const double*)(ws + O_VD64);
    const double* X0 = (const double*)(ws + O_X064);
    const double* HDH = (const double*)(ws + O_HDH);
    const double* HDC = (const double*)(ws + O_HDC);
    const double* GUM = (const double*)(ws + O_GUM);

    const int b = blockIdx.x, tid = threadIdx.x;
    __shared__ float refg_l[128][256];                 // 131072 B (full refg — R11-proven)
    __shared__ __align__(16) float hf[256];            // 1024
    __shared__ __align__(16) char scr[8192];           // gbuf ∪ pA ∪ pQ (live ranges disjoint)
    double (*gbuf)[256] = (double(*)[256])scr;
    float  (*pA)[256]   = (float(*)[256])scr;          // bytes 0..4095
    float  (*pQ)[256]   = (float(*)[256])(scr + 4096); // bytes 4096..8191
    __shared__ __align__(16) float pP[4][256];         // 4096
    __shared__ float u_l[128];
    __shared__ float w_l[128];
    __shared__ unsigned char vis[128];
    __shared__ int lastA;
    const float4* hf4 = (const float4*)hf;

    // stage full refg into LDS (values identical to global -> downstream bit-identical)
    {
        const float4* src = (const float4*)(ws + O_RG + (size_t)b * SL * 256);
        float4* dst = (float4*)&refg_l[0][0];
        for (int i = tid; i < 8192; i += 1024) dst[i] = src[i];
    }
    double c = 0.0;
    if (tid < 256) {
        hf[tid] = (float)HDH[(size_t)b * 256 + tid];
        c = HDC[(size_t)b * 256 + tid];
    }
    if (tid < 128) vis[tid] = 0;
    if (tid == 0) lastA = 0;
    __syncthreads();

    const int g = tid >> 8, j = tid & 255;
    const int kq = tid >> 8, jj = tid & 255;
    const int wave = tid >> 6, lane = tid & 63;
    const int d0 = lane, d1 = lane + 64, d2 = lane + 128, d3 = lane + 192;
    const double vD = VD[tid], x0v = X0[tid];
    const double md0 = MD[tid], md1 = MD[1024 + tid], md2 = MD[2048 + tid], md3 = MD[3072 + tid];
    const float* refp = ws + O_RP + (size_t)b * SL * 256;
    const float* prb = problems + (size_t)b * SL * 4;

    for (int t = 0; t < SL; ++t) {
        // ---- LSTM gate (thread = row; f32 Wh-matvec float4 loads, k-ascending order) ----
        double a0;
        if (t == 0) {
            a0 = x0v;
        } else {
            float4 p = *(const float4*)(prb + (lastA << 2));
            a0 = vD + (double)p.x * md0 + (double)p.y * md1 + (double)p.z * md2 + (double)p.w * md3;
        }
        {
            float f0 = 0.f;
#pragma unroll 4
            for (int k4 = 0; k4 < 64; ++k4) {
                float4 w = Wh4[(k4 << 10) + tid];
                float4 h = hf4[k4];
                f0 = fmaf(h.x, w.x, f0);
                f0 = fmaf(h.y, w.y, f0);
                f0 = fmaf(h.z, w.z, f0);
                f0 = fmaf(h.w, w.w, f0);
            }
            a0 += (double)f0;
        }
        gbuf[g][j] = a0;
        __syncthreads();
        if (tid < 256) {
            double g0 = gbuf[0][tid], g1 = gbuf[1][tid], g2 = gbuf[2][tid], g3 = gbuf[3][tid];
            float ig = sigf((float)g0), fg = sigf((float)g1), gt = tanhf((float)g2), og = sigf((float)g3);
            c = (double)fg * c + (double)ig * (double)gt;
            double h = (double)og * (double)tanhf((float)c);
            hf[tid] = (float)h;
        }
        __syncthreads();

        // ---- qp_g partials: 4 k-chunks of 64, float4 loads (order preserved) ----
        {
            const int kb4 = kq << 4;
            float qa = 0.f;
#pragma unroll 4
            for (int kk4 = 0; kk4 < 16; ++kk4) {
                float4 wq = WQG4[((kb4 + kk4) << 8) + jj];
                float4 h = hf4[kb4 + kk4];
                qa = fmaf(h.x, wq.x, qa);
                qa = fmaf(h.y, wq.y, qa);
                qa = fmaf(h.z, wq.z, qa);
                qa = fmaf(h.w, wq.w, qa);
            }
            pA[kq][jj] = qa;
        }
        __syncthreads();
        // ---- glimpse u: 16 waves x 8 contiguous rows, LDS reads, fast tanh ----
        {
            const float q0 = pA[0][d0] + pA[1][d0] + pA[2][d0] + pA[3][d0] + bq_g[d0], v0 = Vg[d0];
            const float q1 = pA[0][d1] + pA[1][d1] + pA[2][d1] + pA[3][d1] + bq_g[d1], v1 = Vg[d1];
            const float q2 = pA[0][d2] + pA[1][d2] + pA[2][d2] + pA[3][d2] + bq_g[d2], v2 = Vg[d2];
            const float q3 = pA[0][d3] + pA[1][d3] + pA[2][d3] + pA[3][d3] + bq_g[d3], v3 = Vg[d3];
            const int s0 = wave << 3;
            for (int s = s0; s < s0 + 8; ++s) {
                if (vis[s]) continue;   // wave-uniform
                const float* r0 = refg_l[s];
                float part = tanh_fast(q0 + r0[d0]) * 10.f * v0;
                part = fmaf(tanh_fast(q1 + r0[d1]) * 10.f, v1, part);
                part = fmaf(tanh_fast(q2 + r0[d2]) * 10.f, v2, part);
                part = fmaf(tanh_fast(q3 + r0[d3]) * 10.f, v3, part);
                for (int off = 32; off; off >>= 1) part += __shfl_xor(part, off, 64);
                if (lane == 0) u_l[s] = part;
            }
        }
        __syncthreads();
        if (wave == 0) {   // glimpse softmax (R14-proven)
            int s1 = lane, s2 = lane + 64;
            bool v1 = vis[s1], v2 = vis[s2];
            float m = fmaxf(v1 ? -1e30f : u_l[s1], v2 ? -1e30f : u_l[s2]);
            for (int off = 32; off; off >>= 1) m = fmaxf(m, __shfl_xor(m, off, 64));
            float e1 = v1 ? 0.f : expf(u_l[s1] - m);
            float e2 = v2 ? 0.f : expf(u_l[s2] - m);
            float den = e1 + e2;
            for (int off = 32; off; off >>= 1) den += __shfl_xor(den, off, 64);
            w_l[s1] = e1 / den;
            w_l[s2] = e2 / den;
        }
        __syncthreads();
        // ---- q partials: 4 s-chunks of 32 from LDS (bit-identical values) ----
        {
            const int s0 = kq << 5;
            float q = 0.f;
            for (int s = s0; s < s0 + 32; ++s) {
                float w = w_l[s];
                if (w != 0.f) q = fmaf(w, refg_l[s][jj], q);
            }
            pQ[kq][jj] = q;
        }
        __syncthreads();
        // ---- qp_p partials: 4 k-chunks of 64, float4 loads (order preserved) ----
        {
            const int kb4 = kq << 4;
            float qa = 0.f;
            const float4* pQ0 = (const float4*)pQ[0];
            const float4* pQ1 = (const float4*)pQ[1];
            const float4* pQ2 = (const float4*)pQ[2];
            const float4* pQ3 = (const float4*)pQ[3];
#pragma unroll 4
            for (int kk4 = 0; kk4 < 16; ++kk4) {
                int k4 = kb4 + kk4;
                float4 wq = WQP4[(k4 << 8) + jj];
                float4 q0v = pQ0[k4], q1v = pQ1[k4], q2v = pQ2[k4], q3v = pQ3[k4];
                float qkx = ((q0v.x + q1v.x) + q2v.x) + q3v.x;
                float qky = ((q0v.y + q1v.y) + q2v.y) + q3v.y;
                float qkz = ((q0v.z + q1v.z) + q2v.z) + q3v.z;
                float qkw = ((q0v.w + q1v.w) + q2v.w) + q3v.w;
                qa = fmaf(qkx, wq.x, qa);
                qa = fmaf(qky, wq.y, qa);
                qa = fmaf(qkz, wq.z, qa);
                qa = fmaf(qkw, wq.w, qa);
            }
            pP[kq][jj] = qa;
        }
        __syncthreads();
        // ---- pointer logits: 16 waves x 8 contiguous rows, refp global, fast tanh ----
        {
            const float q0 = pP[0][d0] + pP[1][d0] + pP[2][d0] + pP[3][d0] + bq_p[d0], v0 = Vp[d0];
            const float q1 = pP[0][d1] + pP[1][d1] + pP[2][d1] + pP[3][d1] + bq_p[d1], v1 = Vp[d1];
            const float q2 = pP[0][d2] + pP[1][d2] + pP[2][d2] + pP[3][d2] + bq_p[d2], v2 = Vp[d2];
            const float q3 = pP[0][d3] + pP[1][d3] + pP[2][d3] + pP[3][d3] + bq_p[d3], v3 = Vp[d3];
            const int s0 = wave << 3;
            for (int s = s0; s < s0 + 8; ++s) {
                if (vis[s]) continue;
                const float* r0 = refp + (s << 8);
                float part = tanh_fast(q0 + r0[d0]) * 10.f * v0;
                part = fmaf(tanh_fast(q1 + r0[d1]) * 10.f, v1, part);
                part = fmaf(tanh_fast(q2 + r0[d2]) * 10.f, v2, part);
                part = fmaf(tanh_fast(q3 + r0[d3]) * 10.f, v3, part);
                for (int off = 32; off; off >>= 1) part += __shfl_xor(part, off, 64);
                if (lane == 0) u_l[s] = part;
            }
        }
        __syncthreads();
        if (wave == 0) {   // sample (jax-exact; gumbels from bit-identical table)
            int s1 = lane, s2 = lane + 64;
            bool v1 = vis[s1], v2 = vis[s2];
            float m = fmaxf(v1 ? -1e30f : u_l[s1], v2 ? -1e30f : u_l[s2]);
            for (int off = 32; off; off >>= 1) m = fmaxf(m, __shfl_xor(m, off, 64));
            float e1 = v1 ? 0.f : expf(u_l[s1] - m);
            float e2 = v2 ? 0.f : expf(u_l[s2] - m);
            float den = e1 + e2;
            for (int off = 32; off; off >>= 1) den += __shfl_xor(den, off, 64);
            const double* gt = GUM + ((size_t)t << 16) + (b << 7);
            double z1 = v1 ? -1.0e300 : (double)u_l[s1] + gt[s1];
            double z2 = v2 ? -1.0e300 : (double)u_l[s2] + gt[s2];
            double bz; int bi;
            if (z2 > z1) { bz = z2; bi = s2; } else { bz = z1; bi = s1; }
            for (int off = 32; off; off >>= 1) {
                double oz = __shfl_xor(bz, off, 64);
                int oi = __shfl_xor(bi, off, 64);
                if (oz > bz || (oz == bz && oi < bi)) { bz = oz; bi = oi; }
            }
            if (lane == 0) {
                float pr = expf(u_l[bi] - m) / den;
                out[t * NB + b] = pr;
                out[SL * NB + t * NB + b] = (float)bi;
                vis[bi] = 1;
                lastA = bi;
            }
        }
        __syncthreads();
    }
}

extern "C" void kernel_launch(void* const* d_in, const int* in_sizes, int n_in,
                              void* d_out, int out_size, void* d_ws, size_t ws_size,
                              hipStream_t stream) {
    (void)d_ws; (void)ws_size; (void)n_in; (void)in_sizes; (void)out_size;
    const float* problems = (const float*)d_in[0];
    const float* embed_W  = (const float*)d_in[1];
    const float* embed_b  = (const float*)d_in[2];
    const float* Wi_enc   = (const float*)d_in[3];
    const float* Wh_enc   = (const float*)d_in[4];
    const float* b_enc    = (const float*)d_in[5];
    const float* Wi_dec   = (const float*)d_in[6];
    const float* Wh_dec   = (const float*)d_in[7];
    const float* b_dec    = (const float*)d_in[8];
    const float* dec0     = (const float*)d_in[9];
    const float* Wq_g     = (const float*)d_in[10];
    const float* bq_g     = (const float*)d_in[11];
    const float* Wr_g     = (const float*)d_in[12];
    const float* br_g     = (const float*)d_in[13];
    const float* V_g      = (const float*)d_in[14];
    const float* Wq_p     = (const float*)d_in[15];
    const float* bq_p     = (const float*)d_in[16];
    const float* Wr_p     = (const float*)d_in[17];
    const float* br_p     = (const float*)d_in[18];
    const float* V_p      = (const float*)d_in[19];
    float* outp = (float*)d_out;

    hipLaunchKernelGGL(pre_k, dim3(512), dim3(256), 0, stream,
                       embed_W, embed_b, Wi_enc, Wh_enc, b_enc,
                       Wi_dec, Wh_dec, b_dec, dec0, Wr_g, Wr_p, Wq_g, Wq_p);
    hipLaunchKernelGGL(enc_k, dim3(256), dim3(1024), 0, stream, problems);
    hipLaunchKernelGGL(refp_gemm, dim3(1024, 8), dim3(256), 0, stream, br_g, br_p);
    hipLaunchKernelGGL(dec_k, dim3(512), dim3(1024), 0, stream,
                       problems, bq_g, V_g, bq_p, V_p, outp);
}